// Round 1
// baseline (22812.015 us; speedup 1.0000x reference)
//
#include <hip/hip_runtime.h>
#include <cmath>

// ---------------------------------------------------------------------------
// OmniAnomaly forward, fp32 correctness baseline (round 0).
//
// Structure per time step t (serial chain, all on `stream`):
//   1. gru_step<XD>(h_q)  : fused [B,538]x[538,1500] GEMM + GRU cell -> h_q'
//   2. flow_kernel        : q_mean/q_std heads + 3 planar flows -> z_t, ld
//   3. gru_step<ZD>(h_p)  : fused [B,516]x[516,1500] GEMM + GRU cell -> h_p'
//   4. recon_kernel       : p_mean/p_std heads -> recon_mu/std
//
// ws layout (floats): hqA[B*H] hqB[B*H] hpA[B*H] hpB[B*H] z[B*ZD] ld[B]
//   (~8.3 MB; state initialized via t==0 handling since ws is poisoned)
// ---------------------------------------------------------------------------

#define B_  1024
#define T_  100
#define XD_ 38
#define H_  500
#define ZD_ 16
#define L_  3

#define BM 32
#define BN 64
#define BK 16

__device__ __forceinline__ float sigf(float x) {
    return 1.0f / (1.0f + __expf(-x));
}
__device__ __forceinline__ float tanh_(float x) {
    // stable: x>>0 -> 1, x<<0 -> -1 (no inf/inf)
    float e = __expf(2.0f * x);
    return 1.0f - 2.0f / (e + 1.0f);
}
__device__ __forceinline__ float softplus_(float x) {
    // log(1+exp(x)), stable form (matches jax.nn.softplus)
    return fmaxf(x, 0.0f) + log1pf(__expf(-fabsf(x)));
}
__device__ __forceinline__ float grp16_sum(float v) {
    v += __shfl_xor(v, 1, 16);
    v += __shfl_xor(v, 2, 16);
    v += __shfl_xor(v, 4, 16);
    v += __shfl_xor(v, 8, 16);
    return v;
}

// One K-phase of the fused 3-gate GEMM. A:[B x K] row-major (astride),
// Bmat: rows g*H_+j, row-major (bstride). Accumulates into accR/accZ/accN.
__device__ __forceinline__ void gemm_phase(
    const float* __restrict__ A, int astride,
    const float* __restrict__ Bmat, int bstride, int K,
    int m0, int n0, int tid, int tx, int ty,
    float (&accR)[2][4], float (&accZ)[2][4], float (&accN)[2][4],
    float (*As)[BM + 2], float (*Bs)[BK][BN + 4])
{
    const int am = tid >> 3;         // 0..31  (A row within tile)
    const int ak = (tid & 7) * 2;    // 0,2,..,14
    const int nn = tid >> 2;         // 0..63  (B row within tile)
    const int kb = (tid & 3) * 4;    // 0,4,8,12

    for (int k0 = 0; k0 < K; k0 += BK) {
        // stage A tile transposed -> As[k][m]
        {
            int k = k0 + ak;
            const float* src = A + (size_t)(m0 + am) * astride + k;
            float v0 = 0.f, v1 = 0.f;
            if (k < K)     v0 = src[0];
            if (k + 1 < K) v1 = src[1];
            As[ak][am]     = v0;
            As[ak + 1][am] = v1;
        }
        // stage B tiles (3 gates) transposed -> Bs[g][k][n]
        {
            bool rowok = (n0 + nn) < H_;
            #pragma unroll
            for (int g = 0; g < 3; ++g) {
                const float* src = Bmat + (size_t)(g * H_ + n0 + nn) * bstride + k0 + kb;
                float v[4] = {0.f, 0.f, 0.f, 0.f};
                if (rowok) {
                    #pragma unroll
                    for (int i = 0; i < 4; ++i)
                        if (k0 + kb + i < K) v[i] = src[i];
                }
                Bs[g][kb + 0][nn] = v[0];
                Bs[g][kb + 1][nn] = v[1];
                Bs[g][kb + 2][nn] = v[2];
                Bs[g][kb + 3][nn] = v[3];
            }
        }
        __syncthreads();
        #pragma unroll
        for (int kk = 0; kk < BK; ++kk) {
            float2 a2 = *(const float2*)&As[kk][ty * 2];
            float4 b0 = *(const float4*)&Bs[0][kk][tx * 4];
            float4 b1 = *(const float4*)&Bs[1][kk][tx * 4];
            float4 b2 = *(const float4*)&Bs[2][kk][tx * 4];
            float a[2]  = {a2.x, a2.y};
            float r[4]  = {b0.x, b0.y, b0.z, b0.w};
            float z[4]  = {b1.x, b1.y, b1.z, b1.w};
            float nv[4] = {b2.x, b2.y, b2.z, b2.w};
            #pragma unroll
            for (int m = 0; m < 2; ++m)
                #pragma unroll
                for (int n = 0; n < 4; ++n) {
                    accR[m][n] = fmaf(a[m], r[n],  accR[m][n]);
                    accZ[m][n] = fmaf(a[m], z[n],  accZ[m][n]);
                    accN[m][n] = fmaf(a[m], nv[n], accN[m][n]);
                }
        }
        __syncthreads();
    }
}

// Fused GRU step: h_new = GRUCell(x_t, h). Gate order r,z,n (torch nn.GRU).
template <int DX>
__global__ __launch_bounds__(256)
void gru_step_kernel(const float* __restrict__ h,      // [B,H] (ignored if first)
                     const float* __restrict__ xt,     // row b at xt + b*xstride
                     int xstride,
                     const float* __restrict__ Whh,    // [3H,H]
                     const float* __restrict__ Wih,    // [3H,DX]
                     const float* __restrict__ bih,    // [3H]
                     const float* __restrict__ bhh,    // [3H]
                     float* __restrict__ h_new,        // [B,H]
                     int first)
{
    __shared__ float As[BK][BM + 2];
    __shared__ float Bs[3][BK][BN + 4];
    const int tid = threadIdx.x;
    const int tx = tid & 15, ty = tid >> 4;
    const int m0 = blockIdx.x * BM;
    const int n0 = blockIdx.y * BN;

    float accR[2][4] = {}, accZ[2][4] = {}, accNh[2][4] = {}, accNx[2][4] = {};

    if (!first)
        gemm_phase(h, H_, Whh, H_, H_, m0, n0, tid, tx, ty, accR, accZ, accNh, As, Bs);
    gemm_phase(xt, xstride, Wih, DX, DX, m0, n0, tid, tx, ty, accR, accZ, accNx, As, Bs);

    #pragma unroll
    for (int n = 0; n < 4; ++n) {
        int j = n0 + tx * 4 + n;
        if (j >= H_) continue;
        float bR  = bih[j] + bhh[j];
        float bZ  = bih[H_ + j] + bhh[H_ + j];
        float bNx = bih[2 * H_ + j];
        float bNh = bhh[2 * H_ + j];
        #pragma unroll
        for (int m = 0; m < 2; ++m) {
            int b = m0 + ty * 2 + m;
            float rr  = sigf(accR[m][n] + bR);
            float zz  = sigf(accZ[m][n] + bZ);
            float nnv = tanh_(accNx[m][n] + bNx + rr * (accNh[m][n] + bNh));
            float hold = first ? 0.f : h[(size_t)b * H_ + j];
            h_new[(size_t)b * H_ + j] = (1.f - zz) * nnv + zz * hold;
        }
    }
}

// q_mean/q_std heads + reparam + 3 planar flows. 16 lanes per batch row.
__global__ __launch_bounds__(256)
void flow_kernel(const float* __restrict__ hq,      // [B,H]
                 const float* __restrict__ eps,     // [B,T,ZD]
                 const float* __restrict__ Wqm, const float* __restrict__ bqm,
                 const float* __restrict__ Wqs, const float* __restrict__ bqs,
                 const float* __restrict__ fu, const float* __restrict__ fw,
                 const float* __restrict__ fb,
                 float* __restrict__ z_state,       // [B,ZD] ws
                 float* __restrict__ ld_state,      // [B]    ws
                 float* __restrict__ o_z, float* __restrict__ o_zm,
                 float* __restrict__ o_zs, float* __restrict__ o_ld,
                 int t)
{
    int gid = blockIdx.x * blockDim.x + threadIdx.x;
    int b = gid >> 4, zd = gid & 15;

    const float* hrow = hq + (size_t)b * H_;
    const float* wm  = Wqm + zd * (H_ + ZD_);
    const float* wsr = Wqs + zd * (H_ + ZD_);
    float mu = bqm[zd], sq = bqs[zd];
    for (int i = 0; i < H_; i += 4) {
        float4 hv = *(const float4*)(hrow + i);
        float4 a  = *(const float4*)(wm + i);
        float4 c  = *(const float4*)(wsr + i);
        mu += hv.x * a.x + hv.y * a.y + hv.z * a.z + hv.w * a.w;
        sq += hv.x * c.x + hv.y * c.y + hv.z * c.z + hv.w * c.w;
    }
    if (t > 0) {
        #pragma unroll
        for (int i = 0; i < ZD_; ++i) {
            float zi = z_state[b * ZD_ + i];
            mu += zi * wm[H_ + i];
            sq += zi * wsr[H_ + i];
        }
    }
    float sd = softplus_(sq) + 1e-4f;
    size_t oidx = ((size_t)b * T_ + t) * ZD_ + zd;
    float zk = mu + eps[oidx] * sd;
    o_zm[oidx] = mu;
    o_zs[oidx] = sd;

    float ldsum = 0.f;
    #pragma unroll
    for (int k = 0; k < L_; ++k) {
        float w = fw[k * ZD_ + zd];
        float u = fu[k * ZD_ + zd];
        float wu = 0.f, ww = 0.f;
        #pragma unroll
        for (int i = 0; i < ZD_; ++i) {
            float wi = fw[k * ZD_ + i];
            wu += wi * fu[k * ZD_ + i];
            ww += wi * wi;
        }
        float uh = u + (-1.f + softplus_(wu) - wu) * w / (ww + 1e-6f);
        float s  = grp16_sum(zk * w) + fb[k];
        float hh = tanh_(s);
        zk = fmaf(uh, hh, zk);
        float psi = (1.f - hh * hh) * w;
        float det = 1.f + grp16_sum(psi * uh);
        ldsum += logf(fabsf(det) + 1e-6f);
    }
    o_z[oidx] = zk;
    z_state[b * ZD_ + zd] = zk;
    if (zd == 0) {
        float tot = (t == 0 ? 0.f : ld_state[b]) + ldsum;
        ld_state[b] = tot;
        if (t == T_ - 1) o_ld[b] = tot;
    }
}

// recon_mu / recon_std heads: one thread per (b, xd).
__global__ __launch_bounds__(256)
void recon_kernel(const float* __restrict__ hp,     // [B,H]
                  const float* __restrict__ Wpm, const float* __restrict__ bpm,
                  const float* __restrict__ Wps, const float* __restrict__ bps,
                  float* __restrict__ o_rm, float* __restrict__ o_rs, int t)
{
    int gid = blockIdx.x * blockDim.x + threadIdx.x;
    int b = gid / XD_, xd = gid - b * XD_;
    const float* hrow = hp + (size_t)b * H_;
    const float* wm  = Wpm + xd * H_;
    const float* wsr = Wps + xd * H_;
    float m = bpm[xd], s = bps[xd];
    for (int i = 0; i < H_; i += 4) {
        float4 hv = *(const float4*)(hrow + i);
        float4 a  = *(const float4*)(wm + i);
        float4 c  = *(const float4*)(wsr + i);
        m += hv.x * a.x + hv.y * a.y + hv.z * a.z + hv.w * a.w;
        s += hv.x * c.x + hv.y * c.y + hv.z * c.z + hv.w * c.w;
    }
    size_t oidx = ((size_t)b * T_ + t) * XD_ + xd;
    o_rm[oidx] = m;
    o_rs[oidx] = softplus_(s) + 1e-4f;
}

extern "C" void kernel_launch(void* const* d_in, const int* in_sizes, int n_in,
                              void* d_out, int out_size, void* d_ws, size_t ws_size,
                              hipStream_t stream)
{
    (void)in_sizes; (void)n_in; (void)out_size; (void)ws_size;
    const float* x     = (const float*)d_in[0];
    const float* eps   = (const float*)d_in[1];
    const float* Wih_q = (const float*)d_in[2];
    const float* Whh_q = (const float*)d_in[3];
    const float* bih_q = (const float*)d_in[4];
    const float* bhh_q = (const float*)d_in[5];
    const float* Wqm   = (const float*)d_in[6];
    const float* bqm   = (const float*)d_in[7];
    const float* Wqs   = (const float*)d_in[8];
    const float* bqs   = (const float*)d_in[9];
    const float* Wih_p = (const float*)d_in[10];
    const float* Whh_p = (const float*)d_in[11];
    const float* bih_p = (const float*)d_in[12];
    const float* bhh_p = (const float*)d_in[13];
    const float* Wpm   = (const float*)d_in[14];
    const float* bpm   = (const float*)d_in[15];
    const float* Wps   = (const float*)d_in[16];
    const float* bps   = (const float*)d_in[17];
    const float* fu    = (const float*)d_in[18];
    const float* fw    = (const float*)d_in[19];
    const float* fb    = (const float*)d_in[20];

    float* out  = (float*)d_out;
    float* o_rm = out;                 // [B,T,XD]
    float* o_rs = out + 3891200;       // [B,T,XD]
    float* o_z  = out + 7782400;       // [B,T,ZD]
    float* o_zm = out + 9420800;       // [B,T,ZD]
    float* o_zs = out + 11059200;      // [B,T,ZD]
    float* o_ld = out + 12697600;      // [B,1]

    const size_t BH = (size_t)B_ * H_;
    float* wsf  = (float*)d_ws;
    float* hqA  = wsf;
    float* hqB  = hqA + BH;
    float* hpA  = hqB + BH;
    float* hpB  = hpA + BH;
    float* zst  = hpB + BH;            // [B,ZD]
    float* ldst = zst + (size_t)B_ * ZD_;  // [B]

    dim3 ggrid(B_ / BM, (H_ + BN - 1) / BN);  // 32 x 8 = 256 blocks

    for (int t = 0; t < T_; ++t) {
        const float* hq_in  = (t & 1) ? hqB : hqA;
        float*       hq_out = (t & 1) ? hqA : hqB;
        const float* hp_in  = (t & 1) ? hpB : hpA;
        float*       hp_out = (t & 1) ? hpA : hpB;
        int first = (t == 0);

        gru_step_kernel<XD_><<<ggrid, 256, 0, stream>>>(
            hq_in, x + t * XD_, T_ * XD_, Whh_q, Wih_q, bih_q, bhh_q, hq_out, first);

        flow_kernel<<<(B_ * ZD_) / 256, 256, 0, stream>>>(
            hq_out, eps, Wqm, bqm, Wqs, bqs, fu, fw, fb,
            zst, ldst, o_z, o_zm, o_zs, o_ld, t);

        gru_step_kernel<ZD_><<<ggrid, 256, 0, stream>>>(
            hp_in, o_z + t * ZD_, T_ * ZD_, Whh_p, Wih_p, bih_p, bhh_p, hp_out, first);

        recon_kernel<<<(B_ * XD_) / 256, 256, 0, stream>>>(
            hp_out, Wpm, bpm, Wps, bps, o_rm, o_rs, t);
    }
}

// Round 2
// 5145.405 us; speedup vs baseline: 4.4335x; 4.4335x over previous
//
#include <hip/hip_runtime.h>
#include <cmath>

// ---------------------------------------------------------------------------
// OmniAnomaly forward, round 1: bf16 MFMA recurrent GEMMs.
//
// Per step t:
//   flow_recon_kernel: [hq_t, z_{t-1}] @ Wq heads (MFMA) + 3 planar flows
//                      -> z_t (+ recon heads for hp_{t-1} in same launch)
//   step_kernel      : fused dual GEMM-GRU: q-step t+1 (blocks 0..127) and
//                      p-step t (blocks 128..255), MFMA 16x16x32 bf16.
// Weights pre-converted to zero-padded bf16 [n][k] (K padded to 512/64/32).
// h kept fp32 (carry path) + bf16 copy (GEMM A operand).
// ---------------------------------------------------------------------------

#define B_  1024
#define T_  100
#define XD_ 38
#define H_  500
#define ZD_ 16
#define L_  3

typedef short bf16x8 __attribute__((ext_vector_type(8)));
typedef float f32x4  __attribute__((ext_vector_type(4)));
typedef unsigned short ushort;

__device__ __forceinline__ ushort f2bf(float f) {
    union { float f; unsigned u; } v; v.f = f;
    unsigned r = (v.u + 0x7FFF + ((v.u >> 16) & 1)) >> 16;   // RNE
    return (ushort)r;
}
__device__ __forceinline__ float sigf(float x) { return 1.0f / (1.0f + __expf(-x)); }
__device__ __forceinline__ float tanh_(float x) {
    float e = __expf(2.0f * x);
    return 1.0f - 2.0f / (e + 1.0f);
}
__device__ __forceinline__ float softplus_(float x) {
    return fmaxf(x, 0.0f) + log1pf(__expf(-fabsf(x)));
}
__device__ __forceinline__ float grp16_sum(float v) {
    v += __shfl_xor(v, 1, 16);
    v += __shfl_xor(v, 2, 16);
    v += __shfl_xor(v, 4, 16);
    v += __shfl_xor(v, 8, 16);
    return v;
}

// ------------------------- weight conversion -------------------------------
// dst [gates][512][Kpad] bf16, zero padded; src rows g*Jsrc+j, row stride Ksrc.
__global__ __launch_bounds__(256)
void convW_kernel(ushort* __restrict__ dst, const float* __restrict__ src,
                  int Jsrc, int Ksrc, int Kpad)
{
    int i = blockIdx.x * 256 + threadIdx.x;
    int k = i % Kpad;
    int j = (i / Kpad) & 511;
    int g = i / (Kpad * 512);
    float v = (j < Jsrc && k < Ksrc) ? src[(size_t)(g * Jsrc + j) * Ksrc + k] : 0.f;
    dst[i] = f2bf(v);
}

// Wq [32][544]: rows 0..15 = Wqm, 16..31 = Wqs; cols 0..499 = h part,
// 512..527 = z part, rest 0.  Wp [128][512]: rows g*64+j (g: mu/std).
__global__ __launch_bounds__(256)
void convHeads_kernel(ushort* __restrict__ Wq, ushort* __restrict__ Wp,
                      const float* __restrict__ Wqm, const float* __restrict__ Wqs,
                      const float* __restrict__ Wpm, const float* __restrict__ Wps)
{
    int i = blockIdx.x * 256 + threadIdx.x;
    if (i < 32 * 544) {
        int j = i / 544, k = i % 544;
        const float* src = (j < 16) ? Wqm : Wqs;
        int jj = j & 15;
        float v = 0.f;
        if (k < 500)                 v = src[jj * 516 + k];
        else if (k >= 512 && k < 528) v = src[jj * 516 + 500 + (k - 512)];
        Wq[i] = f2bf(v);
    } else {
        int i2 = i - 32 * 544;
        int r = i2 / 512, k = i2 % 512;
        int g = r >> 6, j = r & 63;
        float v = (j < XD_ && k < H_) ? (g ? Wps[j * H_ + k] : Wpm[j * H_ + k]) : 0.f;
        Wp[i2] = f2bf(v);
    }
}

// ------------------------- fused dual GRU step -----------------------------
// mode 0: blocks 0..127 q-step, 128..255 p-step. mode 1: q only. mode 2: p only.
__global__ __launch_bounds__(256)
void step_kernel(int mode, int t_q, int first_q, int first_p,
                 const ushort* __restrict__ hq_in_bf, const float* __restrict__ hq_in_f,
                 float* __restrict__ hq_out_f, ushort* __restrict__ hq_out_bf,
                 const ushort* __restrict__ Whhq, const ushort* __restrict__ Wihq,
                 const float* __restrict__ bihq, const float* __restrict__ bhhq,
                 const float* __restrict__ x,
                 const ushort* __restrict__ hp_in_bf, const float* __restrict__ hp_in_f,
                 float* __restrict__ hp_out_f, ushort* __restrict__ hp_out_bf,
                 const ushort* __restrict__ Whhp, const ushort* __restrict__ Wihp,
                 const float* __restrict__ bihp, const float* __restrict__ bhhp,
                 const ushort* __restrict__ zbf)
{
    __shared__ ushort As[64 * 40];
    __shared__ ushort Bs[3][64 * 40];

    const int tid = threadIdx.x;
    const bool isQ = (mode == 1) || (mode == 0 && blockIdx.x < 128);
    const int bx = isQ ? blockIdx.x : (mode == 2 ? blockIdx.x : blockIdx.x - 128);
    const int m0 = (bx >> 3) * 64;
    const int n0 = (bx & 7) * 64;

    const ushort* A1   = isQ ? hq_in_bf : hp_in_bf;
    const float*  Aold = isQ ? hq_in_f  : hp_in_f;
    float*        outF = isQ ? hq_out_f : hp_out_f;
    ushort*       outB = isQ ? hq_out_bf: hp_out_bf;
    const ushort* W1   = isQ ? Whhq : Whhp;
    const ushort* W2   = isQ ? Wihq : Wihp;
    const float*  bih  = isQ ? bihq : bihp;
    const float*  bhh  = isQ ? bhhq : bhhp;
    const int first    = isQ ? first_q : first_p;
    const int nk2      = isQ ? 2 : 1;
    const int w2kp     = isQ ? 64 : 32;
    const int nk1 = 16;
    const int nktot = nk1 + nk2;
    const int kt0 = first ? nk1 : 0;

    const int srow = tid >> 2, sseg = tid & 3;
    const int w = tid >> 6, ln = tid & 15, qd = (tid >> 4) & 3;
    const int wm = w & 1, wn = w >> 1;

    uint4 pa, pb[3];

    auto load_tile = [&](int kt) {
        if (kt < nk1) {
            pa = *(const uint4*)(A1 + (size_t)(m0 + srow) * 512 + kt * 32 + sseg * 8);
        } else if (isQ) {
            int koff = (kt - nk1) * 32 + sseg * 8;
            const float* xs = x + ((size_t)(m0 + srow) * T_ + t_q) * XD_;
            float v[8];
            #pragma unroll
            for (int i = 0; i < 4; ++i) {
                int d = koff + i * 2;
                if (d + 1 < XD_) { float2 f = *(const float2*)(xs + d); v[2*i] = f.x; v[2*i+1] = f.y; }
                else { v[2*i] = (d < XD_) ? xs[d] : 0.f; v[2*i+1] = 0.f; }
            }
            ushort h[8];
            #pragma unroll
            for (int i = 0; i < 8; ++i) h[i] = f2bf(v[i]);
            pa.x = h[0] | ((unsigned)h[1] << 16);
            pa.y = h[2] | ((unsigned)h[3] << 16);
            pa.z = h[4] | ((unsigned)h[5] << 16);
            pa.w = h[6] | ((unsigned)h[7] << 16);
        } else {
            pa = *(const uint4*)(zbf + (size_t)(m0 + srow) * 32 + sseg * 8);
        }
        const ushort* Wp_ = (kt < nk1) ? W1 : W2;
        int kp = (kt < nk1) ? 512 : w2kp;
        int kk = (kt < nk1) ? kt * 32 : (kt - nk1) * 32;
        #pragma unroll
        for (int g = 0; g < 3; ++g)
            pb[g] = *(const uint4*)(Wp_ + (size_t)(g * 512 + n0 + srow) * kp + kk + sseg * 8);
    };

    f32x4 acc[4][2][2];   // [R,Z,Nh,Nx][mi][ni]
    #pragma unroll
    for (int a = 0; a < 4; ++a)
        #pragma unroll
        for (int mi = 0; mi < 2; ++mi)
            #pragma unroll
            for (int ni = 0; ni < 2; ++ni)
                acc[a][mi][ni] = f32x4{0.f, 0.f, 0.f, 0.f};

    load_tile(kt0);
    for (int kt = kt0; kt < nktot; ++kt) {
        __syncthreads();
        *(uint4*)&As[srow * 40 + sseg * 8] = pa;
        *(uint4*)&Bs[0][srow * 40 + sseg * 8] = pb[0];
        *(uint4*)&Bs[1][srow * 40 + sseg * 8] = pb[1];
        *(uint4*)&Bs[2][srow * 40 + sseg * 8] = pb[2];
        __syncthreads();
        bool ph1 = kt < nk1;
        if (kt + 1 < nktot) load_tile(kt + 1);

        bf16x8 af[2], bfr[3][2];
        #pragma unroll
        for (int mi = 0; mi < 2; ++mi)
            af[mi] = *(const bf16x8*)&As[(wm * 32 + mi * 16 + ln) * 40 + qd * 8];
        #pragma unroll
        for (int g = 0; g < 3; ++g)
            #pragma unroll
            for (int ni = 0; ni < 2; ++ni)
                bfr[g][ni] = *(const bf16x8*)&Bs[g][(wn * 32 + ni * 16 + ln) * 40 + qd * 8];

        int gN = ph1 ? 2 : 3;
        #pragma unroll
        for (int mi = 0; mi < 2; ++mi)
            #pragma unroll
            for (int ni = 0; ni < 2; ++ni) {
                acc[0][mi][ni] = __builtin_amdgcn_mfma_f32_16x16x32_bf16(af[mi], bfr[0][ni], acc[0][mi][ni], 0, 0, 0);
                acc[1][mi][ni] = __builtin_amdgcn_mfma_f32_16x16x32_bf16(af[mi], bfr[1][ni], acc[1][mi][ni], 0, 0, 0);
                acc[gN][mi][ni] = __builtin_amdgcn_mfma_f32_16x16x32_bf16(af[mi], bfr[2][ni], acc[gN][mi][ni], 0, 0, 0);
            }
    }

    // epilogue: GRU cell
    #pragma unroll
    for (int ni = 0; ni < 2; ++ni) {
        int col = n0 + wn * 32 + ni * 16 + ln;
        bool ok = col < H_;
        float bR = 0.f, bZ = 0.f, bNx = 0.f, bNh = 0.f;
        if (ok) {
            bR  = bih[col] + bhh[col];
            bZ  = bih[H_ + col] + bhh[H_ + col];
            bNx = bih[2 * H_ + col];
            bNh = bhh[2 * H_ + col];
        }
        #pragma unroll
        for (int mi = 0; mi < 2; ++mi) {
            int rowb = m0 + wm * 32 + mi * 16 + qd * 4;
            #pragma unroll
            for (int r = 0; r < 4; ++r) {
                int row = rowb + r;
                if (ok) {
                    float rr = sigf(acc[0][mi][ni][r] + bR);
                    float zz = sigf(acc[1][mi][ni][r] + bZ);
                    float nn = tanh_(acc[3][mi][ni][r] + bNx + rr * (acc[2][mi][ni][r] + bNh));
                    float hold = first ? 0.f : Aold[(size_t)row * 512 + col];
                    float hn = (1.f - zz) * nn + zz * hold;
                    outF[(size_t)row * 512 + col] = hn;
                    outB[(size_t)row * 512 + col] = f2bf(hn);
                } else {
                    outB[(size_t)row * 512 + col] = 0;
                }
            }
        }
    }
}

// ---------------- flow (q heads + planar flows) + recon heads --------------
__global__ __launch_bounds__(256)
void flow_recon_kernel(int t, int nFlow, int rt,
                       const ushort* __restrict__ hqbf, ushort* __restrict__ zbf,
                       const ushort* __restrict__ Wq,
                       const float* __restrict__ bqm, const float* __restrict__ bqs,
                       const float* __restrict__ eps,
                       const float* __restrict__ fu, const float* __restrict__ fw,
                       const float* __restrict__ fb,
                       float* __restrict__ ldst,
                       float* __restrict__ o_z, float* __restrict__ o_zm,
                       float* __restrict__ o_zs, float* __restrict__ o_ld,
                       const ushort* __restrict__ hpbf, const ushort* __restrict__ Wp,
                       const float* __restrict__ bpm, const float* __restrict__ bps,
                       float* __restrict__ o_rm, float* __restrict__ o_rs)
{
    __shared__ ushort As[64 * 40];
    __shared__ ushort Bs[2][64 * 40];

    const int tid = threadIdx.x;
    const int srow = tid >> 2, sseg = tid & 3;
    const int w = tid >> 6, ln = tid & 15, qd = (tid >> 4) & 3;

    if ((int)blockIdx.x < nFlow) {
        // ---- flow part: rows m0..m0+64, heads mu(0..15)/sq(16..31) ----
        const int m0 = blockIdx.x * 64;
        const int nk = (t == 0) ? 16 : 17;
        uint4 pa, pbq;
        auto load = [&](int kt) {
            if (kt < 16) pa = *(const uint4*)(hqbf + (size_t)(m0 + srow) * 512 + kt * 32 + sseg * 8);
            else         pa = *(const uint4*)(zbf + (size_t)(m0 + srow) * 32 + sseg * 8);
            if (tid < 128) pbq = *(const uint4*)(Wq + (size_t)srow * 544 + kt * 32 + sseg * 8);
        };
        f32x4 aM = {0.f,0.f,0.f,0.f}, aS = {0.f,0.f,0.f,0.f};
        load(0);
        for (int kt = 0; kt < nk; ++kt) {
            __syncthreads();
            *(uint4*)&As[srow * 40 + sseg * 8] = pa;
            if (tid < 128) *(uint4*)&Bs[0][srow * 40 + sseg * 8] = pbq;
            __syncthreads();
            if (kt + 1 < nk) load(kt + 1);
            bf16x8 a  = *(const bf16x8*)&As[(w * 16 + ln) * 40 + qd * 8];
            bf16x8 bM = *(const bf16x8*)&Bs[0][(ln) * 40 + qd * 8];
            bf16x8 bS = *(const bf16x8*)&Bs[0][(16 + ln) * 40 + qd * 8];
            aM = __builtin_amdgcn_mfma_f32_16x16x32_bf16(a, bM, aM, 0, 0, 0);
            aS = __builtin_amdgcn_mfma_f32_16x16x32_bf16(a, bS, aS, 0, 0, 0);
        }
        // ---- epilogue: reparam + planar flows ----
        int zd = ln;
        float uh[L_], wv[L_], fbv[L_];
        #pragma unroll
        for (int k = 0; k < L_; ++k) {
            float w_ = fw[k * ZD_ + zd];
            float u_ = fu[k * ZD_ + zd];
            float wu = grp16_sum(w_ * u_);
            float ww = grp16_sum(w_ * w_);
            uh[k] = u_ + (-1.f + softplus_(wu) - wu) * w_ / (ww + 1e-6f);
            wv[k] = w_;
            fbv[k] = fb[k];
        }
        #pragma unroll
        for (int r = 0; r < 4; ++r) {
            int b = m0 + w * 16 + qd * 4 + r;
            float mu = aM[r] + bqm[zd];
            float sq = aS[r] + bqs[zd];
            float sd = softplus_(sq) + 1e-4f;
            size_t oi = ((size_t)b * T_ + t) * ZD_ + zd;
            float zk = mu + eps[oi] * sd;
            o_zm[oi] = mu;
            o_zs[oi] = sd;
            float lsum = 0.f;
            #pragma unroll
            for (int k = 0; k < L_; ++k) {
                float hh = tanh_(grp16_sum(zk * wv[k]) + fbv[k]);
                zk = fmaf(uh[k], hh, zk);
                float det = 1.f + grp16_sum((1.f - hh * hh) * wv[k] * uh[k]);
                lsum += logf(fabsf(det) + 1e-6f);
            }
            o_z[oi] = zk;
            zbf[(size_t)b * 32 + zd] = f2bf(zk);
            zbf[(size_t)b * 32 + 16 + zd] = 0;
            if (ln == 0) {
                float tot = (t == 0 ? 0.f : ldst[b]) + lsum;
                ldst[b] = tot;
                if (t == T_ - 1) o_ld[b] = tot;
            }
        }
    } else {
        // ---- recon part for step rt: hp[rt] @ Wp heads ----
        const int rb = blockIdx.x - nFlow;
        const int m0 = rb * 64;
        const int wm = w & 1, wn = w >> 1;
        uint4 pa, pbr[2];
        auto load = [&](int kt) {
            pa = *(const uint4*)(hpbf + (size_t)(m0 + srow) * 512 + kt * 32 + sseg * 8);
            #pragma unroll
            for (int g = 0; g < 2; ++g)
                pbr[g] = *(const uint4*)(Wp + (size_t)(g * 64 + srow) * 512 + kt * 32 + sseg * 8);
        };
        f32x4 acc[2][2][2];
        #pragma unroll
        for (int g = 0; g < 2; ++g)
            #pragma unroll
            for (int mi = 0; mi < 2; ++mi)
                #pragma unroll
                for (int ni = 0; ni < 2; ++ni)
                    acc[g][mi][ni] = f32x4{0.f, 0.f, 0.f, 0.f};
        load(0);
        for (int kt = 0; kt < 16; ++kt) {
            __syncthreads();
            *(uint4*)&As[srow * 40 + sseg * 8] = pa;
            *(uint4*)&Bs[0][srow * 40 + sseg * 8] = pbr[0];
            *(uint4*)&Bs[1][srow * 40 + sseg * 8] = pbr[1];
            __syncthreads();
            if (kt + 1 < 16) load(kt + 1);
            bf16x8 af[2], bg[2][2];
            #pragma unroll
            for (int mi = 0; mi < 2; ++mi)
                af[mi] = *(const bf16x8*)&As[(wm * 32 + mi * 16 + ln) * 40 + qd * 8];
            #pragma unroll
            for (int g = 0; g < 2; ++g)
                #pragma unroll
                for (int ni = 0; ni < 2; ++ni)
                    bg[g][ni] = *(const bf16x8*)&Bs[g][(wn * 32 + ni * 16 + ln) * 40 + qd * 8];
            #pragma unroll
            for (int g = 0; g < 2; ++g)
                #pragma unroll
                for (int mi = 0; mi < 2; ++mi)
                    #pragma unroll
                    for (int ni = 0; ni < 2; ++ni)
                        acc[g][mi][ni] = __builtin_amdgcn_mfma_f32_16x16x32_bf16(af[mi], bg[g][ni], acc[g][mi][ni], 0, 0, 0);
        }
        #pragma unroll
        for (int ni = 0; ni < 2; ++ni) {
            int col = wn * 32 + ni * 16 + ln;
            if (col >= XD_) continue;
            float bm = bpm[col], bs = bps[col];
            #pragma unroll
            for (int mi = 0; mi < 2; ++mi) {
                int rowb = m0 + wm * 32 + mi * 16 + qd * 4;
                #pragma unroll
                for (int r = 0; r < 4; ++r) {
                    int row = rowb + r;
                    size_t oi = ((size_t)row * T_ + rt) * XD_ + col;
                    o_rm[oi] = acc[0][mi][ni][r] + bm;
                    o_rs[oi] = softplus_(acc[1][mi][ni][r] + bs) + 1e-4f;
                }
            }
        }
    }
}

// ---------------------------------------------------------------------------
extern "C" void kernel_launch(void* const* d_in, const int* in_sizes, int n_in,
                              void* d_out, int out_size, void* d_ws, size_t ws_size,
                              hipStream_t stream)
{
    (void)in_sizes; (void)n_in; (void)out_size; (void)ws_size;
    const float* x     = (const float*)d_in[0];
    const float* eps   = (const float*)d_in[1];
    const float* Wih_q = (const float*)d_in[2];
    const float* Whh_q = (const float*)d_in[3];
    const float* bih_q = (const float*)d_in[4];
    const float* bhh_q = (const float*)d_in[5];
    const float* Wqm   = (const float*)d_in[6];
    const float* bqm   = (const float*)d_in[7];
    const float* Wqs   = (const float*)d_in[8];
    const float* bqs   = (const float*)d_in[9];
    const float* Wih_p = (const float*)d_in[10];
    const float* Whh_p = (const float*)d_in[11];
    const float* bih_p = (const float*)d_in[12];
    const float* bhh_p = (const float*)d_in[13];
    const float* Wpm   = (const float*)d_in[14];
    const float* bpm   = (const float*)d_in[15];
    const float* Wps   = (const float*)d_in[16];
    const float* bps   = (const float*)d_in[17];
    const float* fu    = (const float*)d_in[18];
    const float* fw    = (const float*)d_in[19];
    const float* fb    = (const float*)d_in[20];

    float* out  = (float*)d_out;
    float* o_rm = out;
    float* o_rs = out + 3891200;
    float* o_z  = out + 7782400;
    float* o_zm = out + 9420800;
    float* o_zs = out + 11059200;
    float* o_ld = out + 12697600;

    // workspace carve (256B aligned)
    char* p = (char*)d_ws;
    auto alloc = [&](size_t bytes) { void* r = p; p += (bytes + 255) & ~(size_t)255; return r; };
    const size_t HS = (size_t)B_ * 512;
    float*  hqf[2]  = { (float*)alloc(HS * 4), (float*)alloc(HS * 4) };
    float*  hpf[2]  = { (float*)alloc(HS * 4), (float*)alloc(HS * 4) };
    ushort* hqbf[2] = { (ushort*)alloc(HS * 2), (ushort*)alloc(HS * 2) };
    ushort* hpbf[2] = { (ushort*)alloc(HS * 2), (ushort*)alloc(HS * 2) };
    ushort* zbf     = (ushort*)alloc((size_t)B_ * 32 * 2);
    float*  ldst    = (float*)alloc((size_t)B_ * 4);
    ushort* Whhq_bf = (ushort*)alloc((size_t)3 * 512 * 512 * 2);
    ushort* Wihq_bf = (ushort*)alloc((size_t)3 * 512 * 64 * 2);
    ushort* Whhp_bf = (ushort*)alloc((size_t)3 * 512 * 512 * 2);
    ushort* Wihp_bf = (ushort*)alloc((size_t)3 * 512 * 32 * 2);
    ushort* Wq_bf   = (ushort*)alloc((size_t)32 * 544 * 2);
    ushort* Wp_bf   = (ushort*)alloc((size_t)128 * 512 * 2);

    // weight conversion (every call; ws is re-poisoned)
    convW_kernel<<<3072, 256, 0, stream>>>(Whhq_bf, Whh_q, 500, 500, 512);
    convW_kernel<<<384, 256, 0, stream>>>(Wihq_bf, Wih_q, 500, 38, 64);
    convW_kernel<<<3072, 256, 0, stream>>>(Whhp_bf, Whh_p, 500, 500, 512);
    convW_kernel<<<192, 256, 0, stream>>>(Wihp_bf, Wih_p, 500, 16, 32);
    convHeads_kernel<<<324, 256, 0, stream>>>(Wq_bf, Wp_bf, Wqm, Wqs, Wpm, Wps);

    // q step 0 (mode 1)
    step_kernel<<<128, 256, 0, stream>>>(1, 0, 1, 0,
        hqbf[1], hqf[1], hqf[0], hqbf[0], Whhq_bf, Wihq_bf, bih_q, bhh_q, x,
        hpbf[0], hpf[0], hpf[0], hpbf[0], Whhp_bf, Wihp_bf, bih_p, bhh_p, zbf);

    for (int t = 0; t < T_ - 1; ++t) {
        int nblk = (t > 0) ? 32 : 16;
        flow_recon_kernel<<<nblk, 256, 0, stream>>>(t, 16, t - 1,
            hqbf[t & 1], zbf, Wq_bf, bqm, bqs, eps, fu, fw, fb,
            ldst, o_z, o_zm, o_zs, o_ld,
            hpbf[(t + 1) & 1], Wp_bf, bpm, bps, o_rm, o_rs);

        step_kernel<<<256, 256, 0, stream>>>(0, t + 1, 0, (t == 0) ? 1 : 0,
            hqbf[t & 1], hqf[t & 1], hqf[(t + 1) & 1], hqbf[(t + 1) & 1],
            Whhq_bf, Wihq_bf, bih_q, bhh_q, x,
            hpbf[(t + 1) & 1], hpf[(t + 1) & 1], hpf[t & 1], hpbf[t & 1],
            Whhp_bf, Wihp_bf, bih_p, bhh_p, zbf);
    }

    // t = 99: flow + recon(98)
    flow_recon_kernel<<<32, 256, 0, stream>>>(99, 16, 98,
        hqbf[1], zbf, Wq_bf, bqm, bqs, eps, fu, fw, fb,
        ldst, o_z, o_zm, o_zs, o_ld,
        hpbf[0], Wp_bf, bpm, bps, o_rm, o_rs);

    // final p step (t=99, mode 2): reads hp[98] = hpf[0], writes hp[99] = [1]
    step_kernel<<<128, 256, 0, stream>>>(2, 0, 0, 0,
        hqbf[1], hqf[1], hqf[1], hqbf[1], Whhq_bf, Wihq_bf, bih_q, bhh_q, x,
        hpbf[0], hpf[0], hpf[1], hpbf[1], Whhp_bf, Wihp_bf, bih_p, bhh_p, zbf);

    // final recon (t=99)
    flow_recon_kernel<<<16, 256, 0, stream>>>(0, 0, 99,
        hqbf[0], zbf, Wq_bf, bqm, bqs, eps, fu, fw, fb,
        ldst, o_z, o_zm, o_zs, o_ld,
        hpbf[1], Wp_bf, bpm, bps, o_rm, o_rs);
}